// Round 2
// baseline (244.714 us; speedup 1.0000x reference)
//
#include <hip/hip_runtime.h>

// vol[n,d,h,w] = sum_c L[n,c,h,w] * R[n,c,h,w-d], 0 if w<d
// N=4, C=128, H=160, W=320, D=48, fp32 in/out.
//
// Banded-GEMM MFMA formulation, latency-hiding revision:
//  - 2560 blocks = (n,h) x 4 w-quarters (80 w), 320 threads = 5 waves;
//    wave wt owns output w-tile [wb+16wt, wb+16wt+16).
//  - LDS holds R as h2 channel-pairs in TRANSPOSED layout [c2=64][j=128],
//    pitch 132 h2 (528 B, 16B-aligned rows): staging = one ds_write_b128
//    per task (conflict-free), B-frag reads = 4x ds_read_b32 at 2 lanes/bank.
//  - 33.8 KB LDS -> 4 blocks/CU = 20 waves/CU; 4 independently-phased blocks
//    per CU overlap load bursts with compute/store of neighbors.
//  - A (L) fragments loaded directly global->regs, packed f32->f16.
//  - 16 x mfma_f32_16x16x32_f16 per wave; band-masked epilogue transposed
//    through LDS so stores are float4 along w.

#define NN 4
#define CC 128
#define HH 160
#define WW 320
#define DD 48
#define HWs (HH * WW)
#define WB 80        // w extent per block
#define RROWS 128    // staged R j-extent: j in [wb-48, wb+80)
#define RPITCH 132   // h2 per c2-row: 128 + 4 pad (528 B, 16B aligned)
#define RTASKS 2048  // 64 c2 x 32 float4-positions
#define NTHREADS 320

typedef _Float16 h2 __attribute__((ext_vector_type(2)));
typedef _Float16 f16x8 __attribute__((ext_vector_type(8)));
typedef float f32x4 __attribute__((ext_vector_type(4)));
typedef __fp16 h2raw __attribute__((ext_vector_type(2)));

__device__ __forceinline__ h2 pack2(float a, float b) {
  union { h2raw r; h2 h; } u;
  u.r = __builtin_amdgcn_cvt_pkrtz(a, b);  // v_cvt_pkrtz_f16_f32
  return u.h;
}

__global__ __launch_bounds__(NTHREADS, 5)
void corr_kernel(const float* __restrict__ L, const float* __restrict__ R,
                 float* __restrict__ out) {
  // 33,792 B; reused as epilogue transpose buffer (5 x 48x20 f32 = 19,200 B).
  __shared__ __align__(16) h2 Rh[64][RPITCH];

  const int tid = threadIdx.x;
  const int wt  = tid >> 6;   // wave id == w-tile 0..4
  const int ln  = tid & 63;
  const int i16 = ln & 15;    // frag n index (j side)
  const int g   = ln >> 4;    // k-group 0..3

  const int bid = blockIdx.x;
  const int wsplit = bid & 3;
  const int row_nh = bid >> 2;
  const int n = row_nh / HH;
  const int h = row_nh - n * HH;
  const int wb = wsplit * WB;

  const size_t base = (size_t)n * CC * HWs + (size_t)h * WW;
  const float* Rbase = R + base;                      // + c*HWs + col
  const float* Lbase = L + base + wb + 16 * wt + i16; // + c*HWs

  // ---- issue R staging loads (zero-fill j<0; 4-aligned so all-or-none)
  union F4 { float4 f; float a[4]; };
  F4 ra[7], rc[7];
#pragma unroll
  for (int it = 0; it < 7; ++it) {
    int t = tid + it * NTHREADS;
    ra[it].f = make_float4(0.f, 0.f, 0.f, 0.f);
    rc[it].f = make_float4(0.f, 0.f, 0.f, 0.f);
    if (t < RTASKS) {
      int c2 = t >> 5, v = t & 31;
      int col = wb - 48 + 4 * v;
      if (col >= 0) {
        const float* p = Rbase + (size_t)(2 * c2) * HWs + col;
        ra[it].f = *(const float4*)p;
        rc[it].f = *(const float4*)(p + HWs);
      }
    }
  }

  // ---- issue L fragment loads: lane -> L[c = 32ks+8g+e][w0+i16]
  // (16 consecutive lanes read 64 B aligned segments; no LDS round-trip)
  float lv[32];
#pragma unroll
  for (int ks = 0; ks < 4; ++ks)
#pragma unroll
    for (int e = 0; e < 8; ++e)
      lv[ks * 8 + e] = Lbase[(size_t)(32 * ks + 8 * g + e) * HWs];

  // ---- write R to LDS, transposed layout: Rh[c2][j], j = 4v+i.
  // One aligned ds_write_b128 per task; 16B-slot = (33*c2 + v) mod 8 ->
  // exactly 8 lanes per slot -> conflict-free.
  union V4 { float4 f; h2 h[4]; };
#pragma unroll
  for (int it = 0; it < 7; ++it) {
    int t = tid + it * NTHREADS;
    if (t < RTASKS) {
      int c2 = t >> 5, v = t & 31;
      V4 u;
#pragma unroll
      for (int i = 0; i < 4; ++i) u.h[i] = pack2(ra[it].a[i], rc[it].a[i]);
      *(float4*)&Rh[c2][4 * v] = u.f;
    }
  }

  // ---- pack L frags: element e of frag ks <-> channel c = 32ks + 8g + e
  union AU { f16x8 v; h2 h[4]; };
  AU A[4];
#pragma unroll
  for (int ks = 0; ks < 4; ++ks)
#pragma unroll
    for (int j = 0; j < 4; ++j)
      A[ks].h[j] = pack2(lv[ks * 8 + 2 * j], lv[ks * 8 + 2 * j + 1]);

  __syncthreads();

  // ---- MFMA: 4 q-tiles (j-base = wb-48+16(wt+q)) x 4 k-steps.
  // B.h[r] = channels (32ks+8g+2r, +1) at j = 16(wt+q)+i16 — same element
  // order as A. Reads: bank = i16 + 16g + const -> 2 lanes/bank (free).
  f32x4 acc[4] = {};
#pragma unroll
  for (int q = 0; q < 4; ++q) {
    const int j = 16 * (wt + q) + i16;
    union BU { f16x8 v; h2 h[4]; } B;
#pragma unroll
    for (int ks = 0; ks < 4; ++ks) {
      const int r0 = 16 * ks + 4 * g;
#pragma unroll
      for (int r = 0; r < 4; ++r) B.h[r] = Rh[r0 + r][j];
      acc[q] = __builtin_amdgcn_mfma_f32_16x16x32_f16(A[ks].v, B.v, acc[q], 0, 0, 0);
    }
  }

  __syncthreads();  // all B-frag reads done; Rh reused as epilogue buffer

  // ---- epilogue: lane holds D[m=4g+r][n=i16] -> w = w0+4g+r, d = 48-16q+4g+r-i16.
  // Band masks are a disjoint exact cover of d in [0,48). Transpose through LDS
  // ([48 d][20-pad w] f32 per wave) so global stores are float4 along w.
  float* Ep = ((float*)&Rh[0][0]) + wt * (DD * 20);
#pragma unroll
  for (int q = 0; q < 4; ++q)
#pragma unroll
    for (int r = 0; r < 4; ++r) {
      int d = 48 - 16 * q + 4 * g + r - i16;
      if (d >= 0 && d < DD) Ep[d * 20 + 4 * g + r] = acc[q][r];
    }
  // own-wave write->read; compiler inserts the lgkmcnt wait

  const int l4 = ln & 3;
  const int dr = ln >> 2;  // 0..15
  float* outp = out + (size_t)n * DD * HWs + (size_t)h * WW + wb + 16 * wt + 4 * l4;
#pragma unroll
  for (int rr = 0; rr < 3; ++rr) {
    int d = 16 * rr + dr;
    float4 val = *(const float4*)&Ep[d * 20 + 4 * l4];
    *(float4*)&outp[(size_t)d * HWs] = val;
  }
}

extern "C" void kernel_launch(void* const* d_in, const int* in_sizes, int n_in,
                              void* d_out, int out_size, void* d_ws, size_t ws_size,
                              hipStream_t stream) {
  const float* L = (const float*)d_in[0];
  const float* R = (const float*)d_in[1];
  float* out = (float*)d_out;
  corr_kernel<<<dim3(4 * NN * HH), dim3(NTHREADS), 0, stream>>>(L, R, out);
}

// Round 3
// 244.353 us; speedup vs baseline: 1.0015x; 1.0015x over previous
//
#include <hip/hip_runtime.h>

// vol[n,d,h,w] = sum_c L[n,c,h,w] * R[n,c,h,w-d], 0 if w<d
// N=4, C=128, H=160, W=320, D=48, fp32 in/out.
//
// Full-width banded-GEMM with software-pipelined chunks:
//  - 640 blocks = one per (n,h) row -> L and R each fetched exactly once.
//  - 320 threads = 5 waves; 4 w-chunks of 80; wave wt computes w-tile
//    [80k+16wt, 80k+16wt+16) of chunk k via 16x mfma_f32_16x16x32_f16.
//  - R staged as h2 channel-pairs in a ring [64 c2][208 j-slots], pitch 212:
//    staging = ds_write_b128 (bank-balanced), B-frag = 4x ds_read_b32 at
//    exactly 2 lanes/bank (free). Ring: 128 live + 80 prefetch slots.
//  - T14 pipeline per chunk: issue loads(k+1) -> MFMA(k) -> vmcnt+ds_write(k+1)
//    -> barrier -> epilogue(k) (stores overlap next chunk's loads).
//  - A (L) direct global->reg, double-buffered lv[2]; packed f32->f16.
//  - Epilogue transposes D-frags through wave-private LDS scratch so global
//    stores are float4 along w.

#define NN 4
#define CC 128
#define HH 160
#define WW 320
#define DD 48
#define HWs (HH * WW)
#define RS 208   // ring slots (j + 48, wrapped)
#define RP 212   // h2 pitch per c2 row (848 B; 20 mod 32 -> 2-way read banks)
#define NTH 320

typedef _Float16 h2 __attribute__((ext_vector_type(2)));
typedef _Float16 f16x8 __attribute__((ext_vector_type(8)));
typedef float f32x4 __attribute__((ext_vector_type(4)));
typedef __fp16 h2raw __attribute__((ext_vector_type(2)));

__device__ __forceinline__ h2 pack2(float a, float b) {
  union { h2raw r; h2 h; } u;
  u.r = __builtin_amdgcn_cvt_pkrtz(a, b);  // v_cvt_pkrtz_f16_f32
  return u.h;
}

__global__ __launch_bounds__(NTH, 3)
void corr_kernel(const float* __restrict__ L, const float* __restrict__ R,
                 float* __restrict__ out) {
  __shared__ __align__(16) h2 Rh[64][RP];          // 54,272 B ring
  __shared__ __align__(16) float Ep[5][DD * 20];   // 19,200 B epilogue scratch

  const int tid = threadIdx.x;
  const int wt  = tid >> 6;   // wave id == w-tile within chunk
  const int ln  = tid & 63;
  const int i16 = ln & 15;    // frag m/n index
  const int g   = ln >> 4;    // k-group 0..3

  const int bid = blockIdx.x;          // 640 = (n,h)
  const int n = bid / HH;
  const int h = bid - n * HH;
  const size_t base = (size_t)n * CC * HWs + (size_t)h * WW;
  const float* Rb = R + base;                      // + c*HWs + col
  const float* Lb = L + base + 16 * wt + i16;      // + 80k + c*HWs

  union F4 { float4 f; float a[4]; };
  union V4 { float4 f; h2 h[4]; };
  union AU { f16x8 v; h2 h[4]; };
  union BU { f16x8 v; h2 h[4]; };

  // ---- prologue: stage chunk 0 window j in [-48, 80) = 32 f4-positions x 64 c2
  float lv[2][32];
  {
    F4 ra[7], rc[7];
#pragma unroll
    for (int it = 0; it < 7; ++it) {
      int t = tid + it * NTH;
      ra[it].f = make_float4(0.f, 0.f, 0.f, 0.f);
      rc[it].f = make_float4(0.f, 0.f, 0.f, 0.f);
      if (t < 2048) {
        int c2 = t >> 5, v = t & 31;
        int col = 4 * v - 48;
        if (col >= 0) {
          const float* p = Rb + (size_t)(2 * c2) * HWs + col;
          ra[it].f = *(const float4*)p;
          rc[it].f = *(const float4*)(p + HWs);
        }
      }
    }
    // L loads for chunk 0 (stay in flight while R ds_writes drain)
#pragma unroll
    for (int ks = 0; ks < 4; ++ks)
#pragma unroll
      for (int e = 0; e < 8; ++e)
        lv[0][ks * 8 + e] = Lb[(size_t)(32 * ks + 8 * g + e) * HWs];
    // write ring slots [0, 128): slot = j + 48 = 4v
#pragma unroll
    for (int it = 0; it < 7; ++it) {
      int t = tid + it * NTH;
      if (t < 2048) {
        int c2 = t >> 5, v = t & 31;
        V4 u;
#pragma unroll
        for (int i = 0; i < 4; ++i) u.h[i] = pack2(ra[it].a[i], rc[it].a[i]);
        *(float4*)&Rh[c2][4 * v] = u.f;
      }
    }
  }
  __syncthreads();

  // ---- 4 software-pipelined chunks
#pragma unroll
  for (int k = 0; k < 4; ++k) {
    const int cur = k & 1, nxt = cur ^ 1;

    // pack A frags for this chunk: element e of frag ks <-> c = 32ks+8g+e
    AU A[4];
#pragma unroll
    for (int ks = 0; ks < 4; ++ks)
#pragma unroll
      for (int j = 0; j < 4; ++j)
        A[ks].h[j] = pack2(lv[cur][ks * 8 + 2 * j], lv[cur][ks * 8 + 2 * j + 1]);

    // issue next-chunk loads (R: 80 new cols = 20 f4-positions x 64 c2; L: 32 dw)
    F4 ra[4], rc[4];
    if (k < 3) {
      const int j0 = 80 * (k + 1);
#pragma unroll
      for (int it = 0; it < 4; ++it) {
        int t = tid + it * NTH;       // 1280 tasks exactly
        int c2 = t / 20, v = t - 20 * c2;
        const float* p = Rb + (size_t)(2 * c2) * HWs + (j0 + 4 * v);
        ra[it].f = *(const float4*)p;
        rc[it].f = *(const float4*)(p + HWs);
      }
      const float* Lp = Lb + 80 * (k + 1);
#pragma unroll
      for (int ks = 0; ks < 4; ++ks)
#pragma unroll
        for (int e = 0; e < 8; ++e)
          lv[nxt][ks * 8 + e] = Lp[(size_t)(32 * ks + 8 * g + e) * HWs];
    }

    // compute: 4 q-tiles (j = 80k - 48 + 16(wt+q) + i16) x 4 k-steps
    f32x4 acc[4];
#pragma unroll
    for (int q = 0; q < 4; ++q) {
      acc[q] = (f32x4){0.f, 0.f, 0.f, 0.f};
      int s = 80 * k + 16 * (wt + q) + i16;   // = jabs + 48
      if (s >= RS) s -= RS;
      BU B;
#pragma unroll
      for (int ks = 0; ks < 4; ++ks) {
        const int r0 = 16 * ks + 4 * g;
#pragma unroll
        for (int r = 0; r < 4; ++r) B.h[r] = Rh[r0 + r][s];
        acc[q] = __builtin_amdgcn_mfma_f32_16x16x32_f16(A[ks].v, B.v, acc[q], 0, 0, 0);
      }
    }

    // drain next-chunk R loads into the ring (slots disjoint from compute(k))
    if (k < 3) {
#pragma unroll
      for (int it = 0; it < 4; ++it) {
        int t = tid + it * NTH;
        int c2 = t / 20, v = t - 20 * c2;
        int s = 80 * (k + 1) + 48 + 4 * v;
        if (s >= RS) s -= RS;
        V4 u;
#pragma unroll
        for (int i = 0; i < 4; ++i) u.h[i] = pack2(ra[it].a[i], rc[it].a[i]);
        *(float4*)&Rh[c2][s] = u.f;
      }
    }
    __syncthreads();

    // epilogue: lane holds D[m=4g+r][n=i16] -> w = 80k+16wt+4g+r,
    // d = 48-16q+4g+r-i16 (disjoint exact cover of [0,48) over q).
    // Transpose through wave-private scratch -> float4 stores along w.
    float* ep = Ep[wt];
#pragma unroll
    for (int q = 0; q < 4; ++q)
#pragma unroll
      for (int r = 0; r < 4; ++r) {
        int d = 48 - 16 * q + 4 * g + r - i16;
        if (d >= 0 && d < DD) ep[d * 20 + 4 * g + r] = acc[q][r];
      }
    const int l4 = ln & 3;
    const int dr = ln >> 2;  // 0..15
    float* op = out + (size_t)n * DD * HWs + (size_t)h * WW + 80 * k + 16 * wt + 4 * l4;
#pragma unroll
    for (int rr = 0; rr < 3; ++rr) {
      int d = 16 * rr + dr;
      *(float4*)&op[(size_t)d * HWs] = *(const float4*)&ep[d * 20 + 4 * l4];
    }
  }
}

extern "C" void kernel_launch(void* const* d_in, const int* in_sizes, int n_in,
                              void* d_out, int out_size, void* d_ws, size_t ws_size,
                              hipStream_t stream) {
  const float* L = (const float*)d_in[0];
  const float* R = (const float*)d_in[1];
  float* out = (float*)d_out;
  corr_kernel<<<dim3(NN * HH), dim3(NTH), 0, stream>>>(L, R, out);
}